// Round 3
// baseline (1009.100 us; speedup 1.0000x reference)
//
#include <hip/hip_runtime.h>

#define N_ROWS 131072
#define KCODES 1024
#define DIM 64
#define BLOCK 256
#define ROWS_PB 128
#define KHALF (KCODES / 2)

// ||c||^2 for all codes, computed once by a tiny pre-kernel with the exact
// pairwise bit-formula the passing kernel used.
__device__ float g_c2[KCODES];

__global__ void __launch_bounds__(BLOCK)
c2_pre(const float* __restrict__ cb)
{
#pragma clang fp contract(off)
    const int code = blockIdx.x * BLOCK + threadIdx.x;
    const float* c = cb + code * DIM;
    float r0 = c[0]*c[0], r1 = c[1]*c[1], r2 = c[2]*c[2], r3 = c[3]*c[3];
    float r4 = c[4]*c[4], r5 = c[5]*c[5], r6 = c[6]*c[6], r7 = c[7]*c[7];
#pragma unroll
    for (int i = 1; i < 8; ++i) {
        r0 = r0 + c[i*8+0]*c[i*8+0];
        r1 = r1 + c[i*8+1]*c[i*8+1];
        r2 = r2 + c[i*8+2]*c[i*8+2];
        r3 = r3 + c[i*8+3]*c[i*8+3];
        r4 = r4 + c[i*8+4]*c[i*8+4];
        r5 = r5 + c[i*8+5]*c[i*8+5];
        r6 = r6 + c[i*8+6]*c[i*8+6];
        r7 = r7 + c[i*8+7]*c[i*8+7];
    }
    g_c2[code] = ((r0 + r1) + (r2 + r3)) + ((r4 + r5) + (r6 + r7));
}

// h: [32, 64, 64, 64] fp32 (B, D, H, W); codebook: [1024, 64] fp32
// out: z[131072] as float ++ q[131072*64] fp32
//
// Row-per-lane: each lane owns one x-row in 64 VGPRs (loaded once, reused for
// all its codes). Waves 0,1 = rows 0..127 with k in [0,512); waves 2,3 = same
// rows with k in [512,1024) -> 4096 waves = 4/SIMD. Codebook loads are
// uniform-address vector loads (L1/L2 broadcast), consumed CHUNK-WISE
// interleaved with the fma chain so the live set stays ~100 VGPR (Round-2
// lesson: cv[16] upfront = 64 regs -> xr spilled to scratch at the 128 cap).
// ILP-2: codes k and k+1 have independent accumulator chains; results compared
// in k order => np first-index ties preserved. j-loop fully unrolled so xr is
// statically indexed (runtime-indexed arrays go to scratch).
__global__ void
__attribute__((amdgpu_flat_work_group_size(256, 256), amdgpu_waves_per_eu(4)))
vq_main(const float* __restrict__ h,
        const float* __restrict__ cb,
        float* __restrict__ z_out,
        float* __restrict__ q_out)
{
    __shared__ float mbd[ROWS_PB];    // khalf0 best dist
    __shared__ int   mbk[ROWS_PB];    // khalf0 best idx
    __shared__ int   s_idx[ROWS_PB];  // final idx for q gather

    const int tid   = threadIdx.x;
    const int lane  = tid & 63;
    const int wave  = tid >> 6;            // 0..3
    const int khalf = wave >> 1;           // 0: k in [0,512), 1: [512,1024)
    const int rloc  = (wave & 1) * 64 + lane;   // 0..127
    const int row0  = blockIdx.x * ROWS_PB;
    const int row   = row0 + rloc;
    const int bb    = row >> 12;
    const int yx    = row & 4095;

    // ---- x row into registers (coalesced across lanes for each d) ----
    float xr[DIM];
    {
        const float* hb = h + (size_t)bb * (DIM * 4096) + yx;
#pragma unroll
        for (int d = 0; d < DIM; ++d)
            xr[d] = hb[(size_t)d * 4096];
    }

    // ---- Sv = ||x||^2, exact pairwise bit-formula as before ----
    float Sv;
    {
#pragma clang fp contract(off)
        float r0 = xr[0]*xr[0], r1 = xr[1]*xr[1], r2 = xr[2]*xr[2], r3 = xr[3]*xr[3];
        float r4 = xr[4]*xr[4], r5 = xr[5]*xr[5], r6 = xr[6]*xr[6], r7 = xr[7]*xr[7];
#pragma unroll
        for (int i = 1; i < 8; ++i) {
            r0 = r0 + xr[i*8+0]*xr[i*8+0];
            r1 = r1 + xr[i*8+1]*xr[i*8+1];
            r2 = r2 + xr[i*8+2]*xr[i*8+2];
            r3 = r3 + xr[i*8+3]*xr[i*8+3];
            r4 = r4 + xr[i*8+4]*xr[i*8+4];
            r5 = r5 + xr[i*8+5]*xr[i*8+5];
            r6 = r6 + xr[i*8+6]*xr[i*8+6];
            r7 = r7 + xr[i*8+7]*xr[i*8+7];
        }
        Sv = ((r0 + r1) + (r2 + r3)) + ((r4 + r5) + (r6 + r7));
    }

    // ---- argmin over this wave's k-half, two codes in flight ----
    float bd = 3.4e38f;
    int   bk = 0;
    const int kbeg = khalf * KHALF;
    const float4* cb4 = (const float4*)cb;

#pragma unroll 1
    for (int kp = 0; kp < KHALF; kp += 2) {
        const int k = kbeg + kp;
        const float4* cA = cb4 + (size_t)k * 16;   // code k;   code k+1 at +16
        const float c2A = g_c2[k];                 // hoisted: latency under fmas
        const float c2B = g_c2[k + 1];

        float accA = 0.0f, accB = 0.0f;
#pragma unroll
        for (int j = 0; j < 16; ++j) {
            const float4 a = cA[j];
            const float4 b = cA[16 + j];
            accA = __builtin_fmaf(xr[4*j+0], a.x, accA);
            accA = __builtin_fmaf(xr[4*j+1], a.y, accA);
            accA = __builtin_fmaf(xr[4*j+2], a.z, accA);
            accA = __builtin_fmaf(xr[4*j+3], a.w, accA);
            accB = __builtin_fmaf(xr[4*j+0], b.x, accB);
            accB = __builtin_fmaf(xr[4*j+1], b.y, accB);
            accB = __builtin_fmaf(xr[4*j+2], b.z, accB);
            accB = __builtin_fmaf(xr[4*j+3], b.w, accB);
        }

        {
#pragma clang fp contract(off)
            const float tA  = 2.0f * accA;   // exact
            const float uA  = Sv - tA;       // rounded like np
            const float d2A = uA + c2A;
            if (d2A < bd) { bd = d2A; bk = k; }
            const float tB  = 2.0f * accB;
            const float uB  = Sv - tB;
            const float d2B = uB + c2B;
            if (d2B < bd) { bd = d2B; bk = k + 1; }
        }
    }

    // ---- merge k-halves: khalf0 wins ties (smaller k) => np first-index ----
    if (khalf == 0) { mbd[rloc] = bd; mbk[rloc] = bk; }
    __syncthreads();
    if (khalf == 1) {
        const float d0  = mbd[rloc];
        const int   kk0 = mbk[rloc];
        const int   fk  = (bd < d0) ? bk : kk0;
        z_out[row]  = (float)fk;
        s_idx[rloc] = fk;
    }
    __syncthreads();

    // ---- q gather: bit-exact codebook rows, coalesced float4 stores ----
    float4* q4 = (float4*)q_out;
#pragma unroll
    for (int it = 0; it < 8; ++it) {
        const int slot = it * BLOCK + tid;    // 0..2047
        const int rl   = slot >> 4;           // row 0..127
        const int c4   = slot & 15;
        q4[(size_t)(row0 + rl) * 16 + c4] = cb4[(size_t)s_idx[rl] * 16 + c4];
    }
}

extern "C" void kernel_launch(void* const* d_in, const int* in_sizes, int n_in,
                              void* d_out, int out_size, void* d_ws, size_t ws_size,
                              hipStream_t stream) {
    const float* h  = (const float*)d_in[0];
    const float* cb = (const float*)d_in[1];
    float* out   = (float*)d_out;
    float* z_out = out;              // 131072 floats
    float* q_out = out + N_ROWS;     // 131072*64 floats
    (void)d_ws; (void)ws_size;

    c2_pre<<<dim3(KCODES / BLOCK), dim3(BLOCK), 0, stream>>>(cb);
    vq_main<<<dim3(N_ROWS / ROWS_PB), dim3(BLOCK), 0, stream>>>(h, cb, z_out, q_out);
}

// Round 4
// 1008.112 us; speedup vs baseline: 1.0010x; 1.0010x over previous
//
#include <hip/hip_runtime.h>

#define N_ROWS 131072
#define KCODES 1024
#define DIM 64
#define BLOCK 256
#define ROWS_PB 128
#define KHALF (KCODES / 2)

// ||c||^2 for all codes, computed once by a tiny pre-kernel with the exact
// pairwise bit-formula the passing kernel used.
__device__ float g_c2[KCODES];

__global__ void __launch_bounds__(BLOCK)
c2_pre(const float* __restrict__ cb)
{
#pragma clang fp contract(off)
    const int code = blockIdx.x * BLOCK + threadIdx.x;
    const float* c = cb + code * DIM;
    float r0 = c[0]*c[0], r1 = c[1]*c[1], r2 = c[2]*c[2], r3 = c[3]*c[3];
    float r4 = c[4]*c[4], r5 = c[5]*c[5], r6 = c[6]*c[6], r7 = c[7]*c[7];
#pragma unroll
    for (int i = 1; i < 8; ++i) {
        r0 = r0 + c[i*8+0]*c[i*8+0];
        r1 = r1 + c[i*8+1]*c[i*8+1];
        r2 = r2 + c[i*8+2]*c[i*8+2];
        r3 = r3 + c[i*8+3]*c[i*8+3];
        r4 = r4 + c[i*8+4]*c[i*8+4];
        r5 = r5 + c[i*8+5]*c[i*8+5];
        r6 = r6 + c[i*8+6]*c[i*8+6];
        r7 = r7 + c[i*8+7]*c[i*8+7];
    }
    g_c2[code] = ((r0 + r1) + (r2 + r3)) + ((r4 + r5) + (r6 + r7));
}

// h: [32, 64, 64, 64] fp32 (B, D, H, W); codebook: [1024, 64] fp32
// out: z[131072] as float ++ q[131072*64] fp32
//
// Row-per-lane: each lane owns one x-row in 64 VGPRs. Waves 0,1 = rows
// 0..127 with k in [0,512); waves 2,3 = same rows, k in [512,1024).
// Codebook comes in as uniform-address vector loads (L1/L2 broadcast),
// ILP-2 across codes k,k+1 (independent fma chains; compared in k order
// => np first-index ties preserved). j-loop fully unrolled so xr stays
// statically indexed.
//
// ROUND-4 FIX: no amdgpu_waves_per_eu attribute. Round 2/3's
// waves_per_eu(4) forced a 128-VGPR cap below the scheduler's live set
// (xr[64] + in-flight loads) -> allocator spill-cascaded xr to memory
// (VGPR_Count=48, 990us). Default policy lowers occupancy to fit
// pressure WITHOUT spilling -> expect ~130-180 VGPR, 3 waves/SIMD,
// xr genuinely register-resident for the first time.
__global__ void
__attribute__((amdgpu_flat_work_group_size(256, 256)))
vq_main(const float* __restrict__ h,
        const float* __restrict__ cb,
        float* __restrict__ z_out,
        float* __restrict__ q_out)
{
    __shared__ float mbd[ROWS_PB];    // khalf0 best dist
    __shared__ int   mbk[ROWS_PB];    // khalf0 best idx
    __shared__ int   s_idx[ROWS_PB];  // final idx for q gather

    const int tid   = threadIdx.x;
    const int lane  = tid & 63;
    const int wave  = tid >> 6;            // 0..3
    const int khalf = wave >> 1;           // 0: k in [0,512), 1: [512,1024)
    const int rloc  = (wave & 1) * 64 + lane;   // 0..127
    const int row0  = blockIdx.x * ROWS_PB;
    const int row   = row0 + rloc;
    const int bb    = row >> 12;
    const int yx    = row & 4095;

    // ---- x row into registers (coalesced across lanes for each d) ----
    float xr[DIM];
    {
        const float* hb = h + (size_t)bb * (DIM * 4096) + yx;
#pragma unroll
        for (int d = 0; d < DIM; ++d)
            xr[d] = hb[(size_t)d * 4096];
    }

    // ---- Sv = ||x||^2, exact pairwise bit-formula as before ----
    float Sv;
    {
#pragma clang fp contract(off)
        float r0 = xr[0]*xr[0], r1 = xr[1]*xr[1], r2 = xr[2]*xr[2], r3 = xr[3]*xr[3];
        float r4 = xr[4]*xr[4], r5 = xr[5]*xr[5], r6 = xr[6]*xr[6], r7 = xr[7]*xr[7];
#pragma unroll
        for (int i = 1; i < 8; ++i) {
            r0 = r0 + xr[i*8+0]*xr[i*8+0];
            r1 = r1 + xr[i*8+1]*xr[i*8+1];
            r2 = r2 + xr[i*8+2]*xr[i*8+2];
            r3 = r3 + xr[i*8+3]*xr[i*8+3];
            r4 = r4 + xr[i*8+4]*xr[i*8+4];
            r5 = r5 + xr[i*8+5]*xr[i*8+5];
            r6 = r6 + xr[i*8+6]*xr[i*8+6];
            r7 = r7 + xr[i*8+7]*xr[i*8+7];
        }
        Sv = ((r0 + r1) + (r2 + r3)) + ((r4 + r5) + (r6 + r7));
    }

    // ---- argmin over this wave's k-half, two codes in flight ----
    float bd = 3.4e38f;
    int   bk = 0;
    const int kbeg = khalf * KHALF;
    const float4* cb4 = (const float4*)cb;

#pragma unroll 1
    for (int kp = 0; kp < KHALF; kp += 2) {
        const int k = kbeg + kp;
        const float4* cA = cb4 + (size_t)k * 16;   // code k;   code k+1 at +16
        const float c2A = g_c2[k];                 // hoisted: latency under fmas
        const float c2B = g_c2[k + 1];

        float accA = 0.0f, accB = 0.0f;
#pragma unroll
        for (int j = 0; j < 16; ++j) {
            const float4 a = cA[j];
            const float4 b = cA[16 + j];
            accA = __builtin_fmaf(xr[4*j+0], a.x, accA);
            accA = __builtin_fmaf(xr[4*j+1], a.y, accA);
            accA = __builtin_fmaf(xr[4*j+2], a.z, accA);
            accA = __builtin_fmaf(xr[4*j+3], a.w, accA);
            accB = __builtin_fmaf(xr[4*j+0], b.x, accB);
            accB = __builtin_fmaf(xr[4*j+1], b.y, accB);
            accB = __builtin_fmaf(xr[4*j+2], b.z, accB);
            accB = __builtin_fmaf(xr[4*j+3], b.w, accB);
        }

        {
#pragma clang fp contract(off)
            const float tA  = 2.0f * accA;   // exact
            const float uA  = Sv - tA;       // rounded like np
            const float d2A = uA + c2A;
            if (d2A < bd) { bd = d2A; bk = k; }
            const float tB  = 2.0f * accB;
            const float uB  = Sv - tB;
            const float d2B = uB + c2B;
            if (d2B < bd) { bd = d2B; bk = k + 1; }
        }
    }

    // ---- merge k-halves: khalf0 wins ties (smaller k) => np first-index ----
    if (khalf == 0) { mbd[rloc] = bd; mbk[rloc] = bk; }
    __syncthreads();
    if (khalf == 1) {
        const float d0  = mbd[rloc];
        const int   kk0 = mbk[rloc];
        const int   fk  = (bd < d0) ? bk : kk0;
        z_out[row]  = (float)fk;
        s_idx[rloc] = fk;
    }
    __syncthreads();

    // ---- q gather: bit-exact codebook rows, coalesced float4 stores ----
    float4* q4 = (float4*)q_out;
#pragma unroll
    for (int it = 0; it < 8; ++it) {
        const int slot = it * BLOCK + tid;    // 0..2047
        const int rl   = slot >> 4;           // row 0..127
        const int c4   = slot & 15;
        q4[(size_t)(row0 + rl) * 16 + c4] = cb4[(size_t)s_idx[rl] * 16 + c4];
    }
}

extern "C" void kernel_launch(void* const* d_in, const int* in_sizes, int n_in,
                              void* d_out, int out_size, void* d_ws, size_t ws_size,
                              hipStream_t stream) {
    const float* h  = (const float*)d_in[0];
    const float* cb = (const float*)d_in[1];
    float* out   = (float*)d_out;
    float* z_out = out;              // 131072 floats
    float* q_out = out + N_ROWS;     // 131072*64 floats
    (void)d_ws; (void)ws_size;

    c2_pre<<<dim3(KCODES / BLOCK), dim3(BLOCK), 0, stream>>>(cb);
    vq_main<<<dim3(N_ROWS / ROWS_PB), dim3(BLOCK), 0, stream>>>(h, cb, z_out, q_out);
}